// Round 7
// baseline (366.656 us; speedup 1.0000x reference)
//
#include <hip/hip_runtime.h>
#include <hip/hip_bf16.h>

// SingleHeadAttention: B=4, S=4096, D=1024, fp32 in/out, causal, interleaved RoPE.
// R7: fix R6 sgemm256 staging bug — h-offset folded into stage_half's LDS dest
//     (loop was overwriting h0 with h1 and leaving h1 region stale). Schedule
//     (dbuf, counted vmcnt(2), 2 raw barriers/K-tile, setprio) unchanged.

#define SEQ 4096
#define DIM 1024

typedef short bf16x8 __attribute__((ext_vector_type(8)));
typedef float f32x4 __attribute__((ext_vector_type(4)));

__device__ __forceinline__ unsigned short f2bf(float f) {
  unsigned int u = __float_as_uint(f);
  u += 0x7FFFu + ((u >> 16) & 1u);   // RNE
  return (unsigned short)(u >> 16);
}

// bijective XCD swizzle (grids % 8 == 0)
__device__ __forceinline__ int xcd_swz(int bid, int nwg) {
  return (bid & 7) * (nwg >> 3) + (bid >> 3);
}

__device__ __forceinline__ void gll16(const unsigned short* g, unsigned short* l) {
  __builtin_amdgcn_global_load_lds(
      (const __attribute__((address_space(1))) void*)g,
      (__attribute__((address_space(3))) void*)l, 16, 0, 0);
}

__global__ __launch_bounds__(256) void cvt_bf16_kernel(const float* __restrict__ in,
                                                       unsigned short* __restrict__ out,
                                                       int n4) {
  int stride = gridDim.x * blockDim.x;
  for (int j = blockIdx.x * blockDim.x + threadIdx.x; j < n4; j += stride) {
    float4 v = ((const float4*)in)[j];
    ushort4 o;
    o.x = f2bf(v.x); o.y = f2bf(v.y); o.z = f2bf(v.z); o.w = f2bf(v.w);
    ((ushort4*)out)[j] = o;
  }
}

__global__ __launch_bounds__(256) void cvt_w3_kernel(const float* __restrict__ a,
                                                     const float* __restrict__ b,
                                                     const float* __restrict__ c,
                                                     unsigned short* __restrict__ dst) {
  const int n4 = DIM * DIM / 4;
  int stride = gridDim.x * blockDim.x;
  for (int j = blockIdx.x * blockDim.x + threadIdx.x; j < 3 * n4; j += stride) {
    const float* src = j < n4 ? a : (j < 2 * n4 ? b : c);
    const int off = j < n4 ? j : (j < 2 * n4 ? j - n4 : j - 2 * n4);
    float4 v = ((const float4*)src)[off];
    ushort4 o;
    o.x = f2bf(v.x); o.y = f2bf(v.y); o.z = f2bf(v.z); o.w = f2bf(v.w);
    ((ushort4*)dst)[j] = o;
  }
}

// RoPE epilogue: pairs (2i,2i+1) are adjacent lanes (col parity == lane parity)
__device__ __forceinline__ void rope_store(const f32x4 (&acc)[4][4], unsigned short* C,
                                           int rbase, int cbase, int ldc) {
#pragma unroll
  for (int nj = 0; nj < 4; ++nj) {
    const int col = cbase + nj * 16;
    const float invfreq = exp2f(-0.025952563241307517f * (float)(col >> 1));
    const bool odd = (col & 1) != 0;
#pragma unroll
    for (int mi = 0; mi < 4; ++mi)
#pragma unroll
      for (int r = 0; r < 4; ++r) {
        const int row = rbase + mi * 16 + r;
        const float v = acc[mi][nj][r];
        const float p = __shfl_xor(v, 1, 64);
        const float ang = (float)(row & (SEQ - 1)) * invfreq;
        const float sn = __sinf(ang), cs = __cosf(ang);
        C[(long)row * ldc + col] = f2bf(odd ? (v * cs + p * sn) : (v * cs - p * sn));
      }
  }
}

// Fused Q+K projection (+RoPE). 128x128 tile, BK=64, swizzled LDS. [R2-verified]
__global__ __launch_bounds__(256, 2) void qk_proj_kernel(
    const unsigned short* __restrict__ X,
    const unsigned short* __restrict__ Wq,
    const unsigned short* __restrict__ Wk,
    unsigned short* __restrict__ Q,
    unsigned short* __restrict__ Ko) {
  const int bid = xcd_swz(blockIdx.x, gridDim.x);
  const int mt = bid >> 3, nt = bid & 7;
  const int m0 = mt * 128, n0 = nt * 128;

  __shared__ unsigned short sX[128 * 64];
  __shared__ unsigned short sQ[128 * 64];
  __shared__ unsigned short sK[128 * 64];

  const int t = threadIdx.x, w = t >> 6, l = t & 63;
  const int wm = w >> 1, wn = w & 1;
  const int srow = l >> 3;
  const int scol = ((l & 7) ^ srow) * 8;
  const int frow = l & 15;

  f32x4 cq[4][4] = {}, ck[4][4] = {};

  for (int k0 = 0; k0 < DIM; k0 += 64) {
#pragma unroll
    for (int j = 0; j < 4; ++j) {
      const int c = 4 * w + j;
      const int gr = c * 8 + srow;
      gll16(X  + (long)(m0 + gr) * DIM + k0 + scol, &sX[c * 512]);
      gll16(Wq + (long)(n0 + gr) * DIM + k0 + scol, &sQ[c * 512]);
      gll16(Wk + (long)(n0 + gr) * DIM + k0 + scol, &sK[c * 512]);
    }
    __syncthreads();
#pragma unroll
    for (int kk = 0; kk < 2; ++kk) {
      const int slot = (l >> 4) + 4 * kk;
      bf16x8 xa[4], bb[4];
#pragma unroll
      for (int i = 0; i < 4; ++i) {
        const int row = wm * 64 + i * 16 + frow;
        xa[i] = *(const bf16x8*)(&sX[row * 64 + ((slot ^ (row & 7)) << 3)]);
      }
#pragma unroll
      for (int i = 0; i < 4; ++i) {
        const int row = wn * 64 + i * 16 + frow;
        bb[i] = *(const bf16x8*)(&sQ[row * 64 + ((slot ^ (row & 7)) << 3)]);
      }
#pragma unroll
      for (int mi = 0; mi < 4; ++mi)
#pragma unroll
        for (int nj = 0; nj < 4; ++nj)
          cq[mi][nj] = __builtin_amdgcn_mfma_f32_16x16x32_bf16(xa[mi], bb[nj], cq[mi][nj], 0, 0, 0);
#pragma unroll
      for (int i = 0; i < 4; ++i) {
        const int row = wn * 64 + i * 16 + frow;
        bb[i] = *(const bf16x8*)(&sK[row * 64 + ((slot ^ (row & 7)) << 3)]);
      }
#pragma unroll
      for (int mi = 0; mi < 4; ++mi)
#pragma unroll
        for (int nj = 0; nj < 4; ++nj)
          ck[mi][nj] = __builtin_amdgcn_mfma_f32_16x16x32_bf16(xa[mi], bb[nj], ck[mi][nj], 0, 0, 0);
    }
    __syncthreads();
  }

  const int rbase = m0 + wm * 64 + (l >> 4) * 4;
  const int cbase = n0 + wn * 64 + frow;
  rope_store(cq, Q, rbase, cbase, DIM);
  rope_store(ck, Ko, rbase, cbase, DIM);
}

// V^T projection: VT[b][e][s] = sum_k Wv[e][k] * X[b*4096+s][k]. [R2-verified]
__global__ __launch_bounds__(256, 2) void vt_proj_kernel(
    const unsigned short* __restrict__ Wv,
    const unsigned short* __restrict__ X,
    unsigned short* __restrict__ VT) {
  const int bid = xcd_swz(blockIdx.x, gridDim.x);
  const int mt = bid >> 7, nt = bid & 127;
  const int m0 = mt * 128, n0 = nt * 128;

  __shared__ unsigned short sA[128 * 64];
  __shared__ unsigned short sB[128 * 64];

  const int t = threadIdx.x, w = t >> 6, l = t & 63;
  const int wm = w >> 1, wn = w & 1;
  const int srow = l >> 3;
  const int scol = ((l & 7) ^ srow) * 8;
  const int frow = l & 15;

  f32x4 acc[4][4] = {};

  for (int k0 = 0; k0 < DIM; k0 += 64) {
#pragma unroll
    for (int j = 0; j < 4; ++j) {
      const int c = 4 * w + j;
      const int gr = c * 8 + srow;
      gll16(Wv + (long)(m0 + gr) * DIM + k0 + scol, &sA[c * 512]);
      gll16(X  + (long)(n0 + gr) * DIM + k0 + scol, &sB[c * 512]);
    }
    __syncthreads();
#pragma unroll
    for (int kk = 0; kk < 2; ++kk) {
      const int slot = (l >> 4) + 4 * kk;
      bf16x8 av[4], bv[4];
#pragma unroll
      for (int i = 0; i < 4; ++i) {
        const int row = wm * 64 + i * 16 + frow;
        av[i] = *(const bf16x8*)(&sA[row * 64 + ((slot ^ (row & 7)) << 3)]);
      }
#pragma unroll
      for (int i = 0; i < 4; ++i) {
        const int row = wn * 64 + i * 16 + frow;
        bv[i] = *(const bf16x8*)(&sB[row * 64 + ((slot ^ (row & 7)) << 3)]);
      }
#pragma unroll
      for (int mi = 0; mi < 4; ++mi)
#pragma unroll
        for (int nj = 0; nj < 4; ++nj)
          acc[mi][nj] = __builtin_amdgcn_mfma_f32_16x16x32_bf16(av[mi], bv[nj], acc[mi][nj], 0, 0, 0);
    }
    __syncthreads();
  }

  const int rbase = m0 + wm * 64 + (l >> 4) * 4;
  const int cbase = n0 + wn * 64 + frow;
#pragma unroll
  for (int mi = 0; mi < 4; ++mi)
#pragma unroll
    for (int nj = 0; nj < 4; ++nj)
#pragma unroll
      for (int r = 0; r < 4; ++r) {
        const int row = rbase + mi * 16 + r;
        const int col = cbase + nj * 16;
        VT[(long)(col >> 12) * (DIM * SEQ) + (long)row * SEQ + (col & (SEQ - 1))] =
            f2bf(acc[mi][nj][r]);
      }
}

// Scores -> P = exp(s*scale) bf16, packed triangular 128-tiles.
// 256x256 block, BK=64, 8 waves (2Mx4N), dbuf LDS, counted vmcnt, 2 barriers/K-tile.
__global__ __launch_bounds__(512, 2) void sgemm256_kernel(
    const unsigned short* __restrict__ Q,
    const unsigned short* __restrict__ Kg,
    unsigned short* __restrict__ Pp,
    float scale) {
  const int bid = xcd_swz(blockIdx.x, gridDim.x);
  const int b = bid / 136;
  const int t2 = bid - b * 136;
  int I = (int)((sqrtf(8.f * (float)t2 + 1.f) - 1.f) * 0.5f);
  while ((I + 1) * (I + 2) / 2 <= t2) ++I;
  while (I * (I + 1) / 2 > t2) --I;
  const int J = t2 - I * (I + 1) / 2;

  const unsigned short* Ag = Q  + ((long)b * SEQ + I * 256) * DIM;
  const unsigned short* Bg = Kg + ((long)b * SEQ + J * 256) * DIM;

  __shared__ unsigned short sA[2 * 16384];   // [buf][256 rows][64 k] swizzled slots
  __shared__ unsigned short sB[2 * 16384];

  const int t = threadIdx.x, w = t >> 6, l = t & 63;
  const int wm = w >> 2, wn = w & 3;         // wave grid 2M x 4N
  const int frow = l & 15, fgrp = l >> 4;
  const int fsw = frow & 7;
  const int sgr = l >> 3;                    // staging row-in-8
  const int sgc = ((l & 7) ^ sgr) * 8;       // pre-swizzled global k-chunk

  // stage one 128x64 half-tile; LDS dest includes the h offset (R6 bug: it didn't)
  auto stage_half = [&](const unsigned short* gb, unsigned short* lb, int kt, int h) {
#pragma unroll
    for (int q = 0; q < 2; ++q) {
      const int r = h * 128 + q * 64 + w * 8 + sgr;
      gll16(gb + (long)r * DIM + kt * 64 + sgc,
            lb + h * 8192 + q * 4096 + w * 512);
    }
  };

  f32x4 acc[8][4] = {};

  // prologue: stage K-tile 0 into buf0
  stage_half(Ag, sA, 0, 0);
  stage_half(Ag, sA, 0, 1);
  stage_half(Bg, sB, 0, 0);
  stage_half(Bg, sB, 0, 1);

  for (int kt = 0; kt < 16; ++kt) {
    const int cur = kt & 1;
    const int co = cur * 16384, po = (cur ^ 1) * 16384;

    // prefetch h0 of next tile BEFORE the wait -> 2 loads stay in flight
    if (kt < 15) {
      stage_half(Ag, sA + po, kt + 1, 0);
      asm volatile("s_waitcnt vmcnt(2)" ::: "memory");
    } else {
      asm volatile("s_waitcnt vmcnt(0)" ::: "memory");
    }
    __builtin_amdgcn_s_barrier();            // barrier1: buf[cur] writes landed

    // B fragments (wave's 64 cols), full K-step
    bf16x8 bf[4][2];
#pragma unroll
    for (int j = 0; j < 4; ++j) {
      const int rl = (wn & 1) * 64 + j * 16 + frow;
#pragma unroll
      for (int kk = 0; kk < 2; ++kk)
        bf[j][kk] = *(const bf16x8*)
            (&sB[co + (wn >> 1) * 8192 + rl * 64 + (((fgrp + 4 * kk) ^ fsw) << 3)]);
    }
    if (kt < 15) stage_half(Ag, sA + po, kt + 1, 1);

    // A fragments, m-half 0
    bf16x8 af[4][2];
#pragma unroll
    for (int i = 0; i < 4; ++i) {
      const int rl = i * 16 + frow;
#pragma unroll
      for (int kk = 0; kk < 2; ++kk)
        af[i][kk] = *(const bf16x8*)
            (&sA[co + wm * 8192 + rl * 64 + (((fgrp + 4 * kk) ^ fsw) << 3)]);
    }
    __builtin_amdgcn_s_setprio(1);
#pragma unroll
    for (int i = 0; i < 4; ++i)
#pragma unroll
      for (int j = 0; j < 4; ++j)
#pragma unroll
        for (int kk = 0; kk < 2; ++kk)
          acc[i][j] = __builtin_amdgcn_mfma_f32_16x16x32_bf16(af[i][kk], bf[j][kk], acc[i][j], 0, 0, 0);
    __builtin_amdgcn_s_setprio(0);
    if (kt < 15) stage_half(Bg, sB + po, kt + 1, 0);

    // A fragments, m-half 1
#pragma unroll
    for (int i = 0; i < 4; ++i) {
      const int rl = 64 + i * 16 + frow;
#pragma unroll
      for (int kk = 0; kk < 2; ++kk)
        af[i][kk] = *(const bf16x8*)
            (&sA[co + wm * 8192 + rl * 64 + (((fgrp + 4 * kk) ^ fsw) << 3)]);
    }
    if (kt < 15) stage_half(Bg, sB + po, kt + 1, 1);
    __builtin_amdgcn_s_setprio(1);
#pragma unroll
    for (int i = 0; i < 4; ++i)
#pragma unroll
      for (int j = 0; j < 4; ++j)
#pragma unroll
        for (int kk = 0; kk < 2; ++kk)
          acc[4 + i][j] = __builtin_amdgcn_mfma_f32_16x16x32_bf16(af[i][kk], bf[j][kk], acc[4 + i][j], 0, 0, 0);
    __builtin_amdgcn_s_setprio(0);

    asm volatile("" ::: "memory");
    __builtin_amdgcn_s_barrier();            // barrier2: buf[cur] reads done
  }

  // epilogue: exp + causal mask into packed 128-tiles
  const int jh = wn >> 1;
  const bool diagB = (I == J);
  if (diagB && jh > wm) return;              // fully-masked subtile
  const int ip = 2 * I + wm, jp = 2 * J + jh;
  const bool dmask = diagB && (jh == wm);
  unsigned short* Ct = Pp + ((long)(b * 528 + ip * (ip + 1) / 2 + jp) << 14);
#pragma unroll
  for (int m = 0; m < 8; ++m)
#pragma unroll
    for (int j = 0; j < 4; ++j)
#pragma unroll
      for (int r = 0; r < 4; ++r) {
        const int lr = m * 16 + fgrp * 4 + r;
        const int lc = (wn & 1) * 64 + j * 16 + frow;
        float p = __expf(acc[m][j][r] * scale);
        if (dmask && lc > lr) p = 0.f;
        Ct[lr * 128 + lc] = f2bf(p);
      }
}

// Row sums of P: l[q] = sum_kv P[q][kv]. One wave per row; coalesced 4B/lane.
__global__ __launch_bounds__(256) void lsum_kernel(const unsigned short* __restrict__ Pp,
                                                   float* __restrict__ lbuf) {
  const int wid = blockIdx.x * 4 + (threadIdx.x >> 6);
  const int l = threadIdx.x & 63;
  const int b = wid >> 12;
  const int qrow = wid & (SEQ - 1);
  const int i = qrow >> 7, r = qrow & 127;
  const unsigned short* base =
      Pp + ((long)(b * 528 + i * (i + 1) / 2) << 14) + r * 128 + l * 2;

  float sum = 0.f;
  for (int j = 0; j <= i; ++j) {
    const unsigned int v = *(const unsigned int*)(base + ((long)j << 14));
    sum += __uint_as_float(v << 16) + __uint_as_float(v & 0xffff0000u);
  }
#pragma unroll
  for (int o = 32; o; o >>= 1) sum += __shfl_xor(sum, o, 64);
  if (l == 0) lbuf[wid] = sum;
}

// PV: O[q][d] = (1/l[q]) * sum_kv P[q][kv] * V^T[d][kv]. Pure NT GEMM. [R5-verified]
__global__ __launch_bounds__(256, 2) void pv_kernel(
    const unsigned short* __restrict__ Pp,
    const unsigned short* __restrict__ VT,
    const float* __restrict__ lbuf,
    float* __restrict__ O,
    int nb) {
  const int d = blockIdx.x & 7;
  const int qr = blockIdx.x >> 3;
  const int b = qr % nb;
  const int i = 31 - qr / nb;
  const int m0 = i * 128, n0 = d * 128;
  const int Keff = (i + 1) * 128;

  const unsigned short* At = Pp + ((long)(b * 528 + i * (i + 1) / 2) << 14);
  const unsigned short* Bp = VT + (long)b * DIM * SEQ + (long)n0 * SEQ;
  const float* lq = lbuf + (long)b * SEQ + m0;
  float* Op = O + ((long)b * SEQ + m0) * DIM;

  __shared__ unsigned short sA[128 * 64];
  __shared__ unsigned short sB[128 * 64];

  const int t = threadIdx.x, w = t >> 6, l = t & 63;
  const int wm = w >> 1, wn = w & 1;
  const int srow = l >> 3;
  const int scol = ((l & 7) ^ srow) * 8;
  const int frow = l & 15;

  f32x4 acc[4][4] = {};

  for (int k0 = 0; k0 < Keff; k0 += 64) {
    const unsigned short* Ak = At + ((long)(k0 >> 7) << 14) + (k0 & 64);
#pragma unroll
    for (int j = 0; j < 4; ++j) {
      const int c = 4 * w + j;
      const int gr = c * 8 + srow;
      gll16(Ak + (long)gr * 128 + scol, &sA[c * 512]);
      gll16(Bp + (long)gr * SEQ + k0 + scol, &sB[c * 512]);
    }
    __syncthreads();
#pragma unroll
    for (int kk = 0; kk < 2; ++kk) {
      const int slot = (l >> 4) + 4 * kk;
      bf16x8 av[4], bv[4];
#pragma unroll
      for (int ii = 0; ii < 4; ++ii) {
        const int row = wm * 64 + ii * 16 + frow;
        av[ii] = *(const bf16x8*)(&sA[row * 64 + ((slot ^ (row & 7)) << 3)]);
      }
#pragma unroll
      for (int ii = 0; ii < 4; ++ii) {
        const int row = wn * 64 + ii * 16 + frow;
        bv[ii] = *(const bf16x8*)(&sB[row * 64 + ((slot ^ (row & 7)) << 3)]);
      }
#pragma unroll
      for (int mi = 0; mi < 4; ++mi)
#pragma unroll
        for (int nj = 0; nj < 4; ++nj)
          acc[mi][nj] = __builtin_amdgcn_mfma_f32_16x16x32_bf16(av[mi], bv[nj], acc[mi][nj], 0, 0, 0);
    }
    __syncthreads();
  }

  const int rb = wm * 64 + (l >> 4) * 4;
  const int cb = n0 + wn * 64 + frow;
#pragma unroll
  for (int mi = 0; mi < 4; ++mi)
#pragma unroll
    for (int r = 0; r < 4; ++r) {
      const int row = rb + mi * 16 + r;
      const float inv = 1.0f / lq[row];
#pragma unroll
      for (int nj = 0; nj < 4; ++nj)
        Op[(long)row * DIM + cb + nj * 16] = acc[mi][nj][r] * inv;
    }
}

extern "C" void kernel_launch(void* const* d_in, const int* in_sizes, int n_in,
                              void* d_out, int out_size, void* d_ws, size_t ws_size,
                              hipStream_t stream) {
  (void)in_sizes; (void)n_in; (void)out_size;
  const float* x  = (const float*)d_in[0];
  const float* wq = (const float*)d_in[1];
  const float* wk = (const float*)d_in[2];
  const float* wv = (const float*)d_in[3];
  float* out = (float*)d_out;

  const long NTOK = (long)SEQ * 4;
  unsigned short* xb  = (unsigned short*)d_ws;
  unsigned short* Qb  = xb + NTOK * DIM;
  unsigned short* Kb  = Qb + NTOK * DIM;
  unsigned short* VT  = Kb + NTOK * DIM;
  unsigned short* w3  = VT + NTOK * DIM;
  unsigned short* wqb = w3;
  unsigned short* wkb = wqb + DIM * DIM;
  unsigned short* wvb = wkb + DIM * DIM;
  unsigned short* Pp  = w3;

  const size_t base_b = 4ull * NTOK * DIM * 2ull;
  const size_t full_need = base_b + (2112ull << 14) * 2 + 4ull * NTOK;
  const bool full = ws_size >= full_need;
  const float scale = 0.03125f;

  cvt_bf16_kernel<<<2048, 256, 0, stream>>>(x, xb, (int)(NTOK * DIM / 4));
  cvt_w3_kernel<<<1024, 256, 0, stream>>>(wq, wk, wv, wqb);

  qk_proj_kernel<<<128 * 8, 256, 0, stream>>>(xb, wqb, wkb, Qb, Kb);
  vt_proj_kernel<<<8 * 128, 256, 0, stream>>>(wvb, xb, VT);

  if (full) {
    float* lbuf = (float*)(Pp + (2112ull << 14));
    sgemm256_kernel<<<4 * 136, 512, 0, stream>>>(Qb, Kb, Pp, scale);
    lsum_kernel<<<4096, 256, 0, stream>>>(Pp, lbuf);
    pv_kernel<<<8 * 4 * 32, 256, 0, stream>>>(Pp, VT, lbuf, out, 4);
  } else {
    float* lbuf = (float*)(Pp + (528ull << 14));
    for (int b = 0; b < 4; ++b) {
      sgemm256_kernel<<<136, 512, 0, stream>>>(
          Qb + (long)b * SEQ * DIM, Kb + (long)b * SEQ * DIM, Pp, scale);
      lsum_kernel<<<1024, 256, 0, stream>>>(Pp, lbuf);
      pv_kernel<<<8 * 32, 256, 0, stream>>>(
          Pp, VT + (long)b * DIM * SEQ, lbuf, out + (long)b * SEQ * DIM, 1);
    }
  }
}

// Round 8
// 356.007 us; speedup vs baseline: 1.0299x; 1.0299x over previous
//
#include <hip/hip_runtime.h>
#include <hip/hip_bf16.h>

// SingleHeadAttention: B=4, S=4096, D=1024, fp32 in/out, causal, interleaved RoPE.
// R8: revert sgemm to the proven 128^2 engine (R7's 256^2 was tail-bound: 1 blk/CU,
//     544 blocks = 2.125 rounds, 664 TF < 875). pv widened to 128x256 tiles
//     (P re-read 8x -> 4x) with d-innermost XCD-chunked work order (P L2-reuse).

#define SEQ 4096
#define DIM 1024

typedef short bf16x8 __attribute__((ext_vector_type(8)));
typedef float f32x4 __attribute__((ext_vector_type(4)));

__device__ __forceinline__ unsigned short f2bf(float f) {
  unsigned int u = __float_as_uint(f);
  u += 0x7FFFu + ((u >> 16) & 1u);   // RNE
  return (unsigned short)(u >> 16);
}

// bijective XCD swizzle (grids % 8 == 0): XCD x gets work [x*nwg/8,(x+1)*nwg/8)
__device__ __forceinline__ int xcd_swz(int bid, int nwg) {
  return (bid & 7) * (nwg >> 3) + (bid >> 3);
}

__device__ __forceinline__ void gll16(const unsigned short* g, unsigned short* l) {
  __builtin_amdgcn_global_load_lds(
      (const __attribute__((address_space(1))) void*)g,
      (__attribute__((address_space(3))) void*)l, 16, 0, 0);
}

__global__ __launch_bounds__(256) void cvt_bf16_kernel(const float* __restrict__ in,
                                                       unsigned short* __restrict__ out,
                                                       int n4) {
  int stride = gridDim.x * blockDim.x;
  for (int j = blockIdx.x * blockDim.x + threadIdx.x; j < n4; j += stride) {
    float4 v = ((const float4*)in)[j];
    ushort4 o;
    o.x = f2bf(v.x); o.y = f2bf(v.y); o.z = f2bf(v.z); o.w = f2bf(v.w);
    ((ushort4*)out)[j] = o;
  }
}

__global__ __launch_bounds__(256) void cvt_w3_kernel(const float* __restrict__ a,
                                                     const float* __restrict__ b,
                                                     const float* __restrict__ c,
                                                     unsigned short* __restrict__ dst) {
  const int n4 = DIM * DIM / 4;
  int stride = gridDim.x * blockDim.x;
  for (int j = blockIdx.x * blockDim.x + threadIdx.x; j < 3 * n4; j += stride) {
    const float* src = j < n4 ? a : (j < 2 * n4 ? b : c);
    const int off = j < n4 ? j : (j < 2 * n4 ? j - n4 : j - 2 * n4);
    float4 v = ((const float4*)src)[off];
    ushort4 o;
    o.x = f2bf(v.x); o.y = f2bf(v.y); o.z = f2bf(v.z); o.w = f2bf(v.w);
    ((ushort4*)dst)[j] = o;
  }
}

// RoPE epilogue: pairs (2i,2i+1) are adjacent lanes (col parity == lane parity)
__device__ __forceinline__ void rope_store(const f32x4 (&acc)[4][4], unsigned short* C,
                                           int rbase, int cbase, int ldc) {
#pragma unroll
  for (int nj = 0; nj < 4; ++nj) {
    const int col = cbase + nj * 16;
    const float invfreq = exp2f(-0.025952563241307517f * (float)(col >> 1));
    const bool odd = (col & 1) != 0;
#pragma unroll
    for (int mi = 0; mi < 4; ++mi)
#pragma unroll
      for (int r = 0; r < 4; ++r) {
        const int row = rbase + mi * 16 + r;
        const float v = acc[mi][nj][r];
        const float p = __shfl_xor(v, 1, 64);
        const float ang = (float)(row & (SEQ - 1)) * invfreq;
        const float sn = __sinf(ang), cs = __cosf(ang);
        C[(long)row * ldc + col] = f2bf(odd ? (v * cs + p * sn) : (v * cs - p * sn));
      }
  }
}

// Fused Q+K projection (+RoPE). 128x128 tile, BK=64, swizzled LDS. [R2-verified]
__global__ __launch_bounds__(256, 2) void qk_proj_kernel(
    const unsigned short* __restrict__ X,
    const unsigned short* __restrict__ Wq,
    const unsigned short* __restrict__ Wk,
    unsigned short* __restrict__ Q,
    unsigned short* __restrict__ Ko) {
  const int bid = xcd_swz(blockIdx.x, gridDim.x);
  const int mt = bid >> 3, nt = bid & 7;
  const int m0 = mt * 128, n0 = nt * 128;

  __shared__ unsigned short sX[128 * 64];
  __shared__ unsigned short sQ[128 * 64];
  __shared__ unsigned short sK[128 * 64];

  const int t = threadIdx.x, w = t >> 6, l = t & 63;
  const int wm = w >> 1, wn = w & 1;
  const int srow = l >> 3;
  const int scol = ((l & 7) ^ srow) * 8;
  const int frow = l & 15;

  f32x4 cq[4][4] = {}, ck[4][4] = {};

  for (int k0 = 0; k0 < DIM; k0 += 64) {
#pragma unroll
    for (int j = 0; j < 4; ++j) {
      const int c = 4 * w + j;
      const int gr = c * 8 + srow;
      gll16(X  + (long)(m0 + gr) * DIM + k0 + scol, &sX[c * 512]);
      gll16(Wq + (long)(n0 + gr) * DIM + k0 + scol, &sQ[c * 512]);
      gll16(Wk + (long)(n0 + gr) * DIM + k0 + scol, &sK[c * 512]);
    }
    __syncthreads();
#pragma unroll
    for (int kk = 0; kk < 2; ++kk) {
      const int slot = (l >> 4) + 4 * kk;
      bf16x8 xa[4], bb[4];
#pragma unroll
      for (int i = 0; i < 4; ++i) {
        const int row = wm * 64 + i * 16 + frow;
        xa[i] = *(const bf16x8*)(&sX[row * 64 + ((slot ^ (row & 7)) << 3)]);
      }
#pragma unroll
      for (int i = 0; i < 4; ++i) {
        const int row = wn * 64 + i * 16 + frow;
        bb[i] = *(const bf16x8*)(&sQ[row * 64 + ((slot ^ (row & 7)) << 3)]);
      }
#pragma unroll
      for (int mi = 0; mi < 4; ++mi)
#pragma unroll
        for (int nj = 0; nj < 4; ++nj)
          cq[mi][nj] = __builtin_amdgcn_mfma_f32_16x16x32_bf16(xa[mi], bb[nj], cq[mi][nj], 0, 0, 0);
#pragma unroll
      for (int i = 0; i < 4; ++i) {
        const int row = wn * 64 + i * 16 + frow;
        bb[i] = *(const bf16x8*)(&sK[row * 64 + ((slot ^ (row & 7)) << 3)]);
      }
#pragma unroll
      for (int mi = 0; mi < 4; ++mi)
#pragma unroll
        for (int nj = 0; nj < 4; ++nj)
          ck[mi][nj] = __builtin_amdgcn_mfma_f32_16x16x32_bf16(xa[mi], bb[nj], ck[mi][nj], 0, 0, 0);
    }
    __syncthreads();
  }

  const int rbase = m0 + wm * 64 + (l >> 4) * 4;
  const int cbase = n0 + wn * 64 + frow;
  rope_store(cq, Q, rbase, cbase, DIM);
  rope_store(ck, Ko, rbase, cbase, DIM);
}

// V^T projection: VT[b][e][s] = sum_k Wv[e][k] * X[b*4096+s][k]. [R2-verified]
__global__ __launch_bounds__(256, 2) void vt_proj_kernel(
    const unsigned short* __restrict__ Wv,
    const unsigned short* __restrict__ X,
    unsigned short* __restrict__ VT) {
  const int bid = xcd_swz(blockIdx.x, gridDim.x);
  const int mt = bid >> 7, nt = bid & 127;
  const int m0 = mt * 128, n0 = nt * 128;

  __shared__ unsigned short sA[128 * 64];
  __shared__ unsigned short sB[128 * 64];

  const int t = threadIdx.x, w = t >> 6, l = t & 63;
  const int wm = w >> 1, wn = w & 1;
  const int srow = l >> 3;
  const int scol = ((l & 7) ^ srow) * 8;
  const int frow = l & 15;

  f32x4 acc[4][4] = {};

  for (int k0 = 0; k0 < DIM; k0 += 64) {
#pragma unroll
    for (int j = 0; j < 4; ++j) {
      const int c = 4 * w + j;
      const int gr = c * 8 + srow;
      gll16(Wv + (long)(m0 + gr) * DIM + k0 + scol, &sA[c * 512]);
      gll16(X  + (long)(n0 + gr) * DIM + k0 + scol, &sB[c * 512]);
    }
    __syncthreads();
#pragma unroll
    for (int kk = 0; kk < 2; ++kk) {
      const int slot = (l >> 4) + 4 * kk;
      bf16x8 av[4], bv[4];
#pragma unroll
      for (int i = 0; i < 4; ++i) {
        const int row = wm * 64 + i * 16 + frow;
        av[i] = *(const bf16x8*)(&sA[row * 64 + ((slot ^ (row & 7)) << 3)]);
      }
#pragma unroll
      for (int i = 0; i < 4; ++i) {
        const int row = wn * 64 + i * 16 + frow;
        bv[i] = *(const bf16x8*)(&sB[row * 64 + ((slot ^ (row & 7)) << 3)]);
      }
#pragma unroll
      for (int mi = 0; mi < 4; ++mi)
#pragma unroll
        for (int nj = 0; nj < 4; ++nj)
          acc[mi][nj] = __builtin_amdgcn_mfma_f32_16x16x32_bf16(av[mi], bv[nj], acc[mi][nj], 0, 0, 0);
    }
    __syncthreads();
  }

  const int rbase = m0 + wm * 64 + (l >> 4) * 4;
  const int cbase = n0 + wn * 64 + frow;
#pragma unroll
  for (int mi = 0; mi < 4; ++mi)
#pragma unroll
    for (int nj = 0; nj < 4; ++nj)
#pragma unroll
      for (int r = 0; r < 4; ++r) {
        const int row = rbase + mi * 16 + r;
        const int col = cbase + nj * 16;
        VT[(long)(col >> 12) * (DIM * SEQ) + (long)row * SEQ + (col & (SEQ - 1))] =
            f2bf(acc[mi][nj][r]);
      }
}

// Scores -> P = exp(s*scale) bf16, packed triangular 128-tiles. [R5-verified]
__global__ __launch_bounds__(256, 2) void sgemm_packed_kernel(
    const unsigned short* __restrict__ Q,
    const unsigned short* __restrict__ K,
    unsigned short* __restrict__ Pp,
    float scale) {
  const int t0 = xcd_swz(blockIdx.x, gridDim.x);
  const int b = t0 / 528;
  const int t2 = t0 - b * 528;
  int i = (int)((sqrtf(8.f * (float)t2 + 1.f) - 1.f) * 0.5f);
  while ((i + 1) * (i + 2) / 2 <= t2) ++i;
  while (i * (i + 1) / 2 > t2) --i;
  const int j = t2 - i * (i + 1) / 2;

  const unsigned short* A = Q + ((long)b * SEQ + i * 128) * DIM;
  const unsigned short* B = K + ((long)b * SEQ + j * 128) * DIM;

  __shared__ unsigned short sA[128 * 64];
  __shared__ unsigned short sB[128 * 64];

  const int t = threadIdx.x, w = t >> 6, l = t & 63;
  const int wm = w >> 1, wn = w & 1;
  const int srow = l >> 3;
  const int scol = ((l & 7) ^ srow) * 8;
  const int frow = l & 15;

  f32x4 acc[4][4] = {};

  for (int k0 = 0; k0 < DIM; k0 += 64) {
#pragma unroll
    for (int jj = 0; jj < 4; ++jj) {
      const int c = 4 * w + jj;
      const int gr = c * 8 + srow;
      gll16(A + (long)gr * DIM + k0 + scol, &sA[c * 512]);
      gll16(B + (long)gr * DIM + k0 + scol, &sB[c * 512]);
    }
    __syncthreads();
#pragma unroll
    for (int kk = 0; kk < 2; ++kk) {
      const int slot = (l >> 4) + 4 * kk;
      bf16x8 av[4], bv[4];
#pragma unroll
      for (int ii = 0; ii < 4; ++ii) {
        const int row = wm * 64 + ii * 16 + frow;
        av[ii] = *(const bf16x8*)(&sA[row * 64 + ((slot ^ (row & 7)) << 3)]);
      }
#pragma unroll
      for (int ii = 0; ii < 4; ++ii) {
        const int row = wn * 64 + ii * 16 + frow;
        bv[ii] = *(const bf16x8*)(&sB[row * 64 + ((slot ^ (row & 7)) << 3)]);
      }
#pragma unroll
      for (int mi = 0; mi < 4; ++mi)
#pragma unroll
        for (int nj = 0; nj < 4; ++nj)
          acc[mi][nj] = __builtin_amdgcn_mfma_f32_16x16x32_bf16(av[mi], bv[nj], acc[mi][nj], 0, 0, 0);
    }
    __syncthreads();
  }

  unsigned short* Ct = Pp + ((long)(b * 528 + t2) << 14);
  const int rb = wm * 64 + (l >> 4) * 4;
  const int cb = wn * 64 + frow;
  const bool diagt = (j == i);
#pragma unroll
  for (int mi = 0; mi < 4; ++mi)
#pragma unroll
    for (int nj = 0; nj < 4; ++nj)
#pragma unroll
      for (int r = 0; r < 4; ++r) {
        const int row = rb + mi * 16 + r;
        const int col = cb + nj * 16;
        float p = __expf(acc[mi][nj][r] * scale);
        if (diagt && col > row) p = 0.f;
        Ct[row * 128 + col] = f2bf(p);
      }
}

// Row sums of P: l[q] = sum_kv P[q][kv]. One wave per row; coalesced 4B/lane.
__global__ __launch_bounds__(256) void lsum_kernel(const unsigned short* __restrict__ Pp,
                                                   float* __restrict__ lbuf) {
  const int wid = blockIdx.x * 4 + (threadIdx.x >> 6);
  const int l = threadIdx.x & 63;
  const int b = wid >> 12;
  const int qrow = wid & (SEQ - 1);
  const int i = qrow >> 7, r = qrow & 127;
  const unsigned short* base =
      Pp + ((long)(b * 528 + i * (i + 1) / 2) << 14) + r * 128 + l * 2;

  float sum = 0.f;
  for (int j = 0; j <= i; ++j) {
    const unsigned int v = *(const unsigned int*)(base + ((long)j << 14));
    sum += __uint_as_float(v << 16) + __uint_as_float(v & 0xffff0000u);
  }
#pragma unroll
  for (int o = 32; o; o >>= 1) sum += __shfl_xor(sum, o, 64);
  if (l == 0) lbuf[wid] = sum;
}

// PV: O[q][d] = (1/l[q]) * sum_kv P[q][kv] * V^T[d][kv]. Pure NT GEMM.
// 128q x 256d tile, 4 waves (2m x 2n), acc 4x8. Work = ((ii*nb+b)<<2)|d with
// d innermost -> the 4 d-blocks of one (b,i) are adjacent in the XCD work chunk
// (P tiles L2-hit after first d). ii ascending = i descending (balance).
__global__ __launch_bounds__(256, 2) void pv_kernel(
    const unsigned short* __restrict__ Pp,
    const unsigned short* __restrict__ VT,
    const float* __restrict__ lbuf,
    float* __restrict__ O,
    int nb) {
  const int work = xcd_swz(blockIdx.x, gridDim.x);
  const int d = work & 3;
  const int rest = work >> 2;
  const int b = rest & (nb - 1);
  const int i = 31 - rest / nb;
  const int m0 = i * 128, n0 = d * 256;
  const int Keff = (i + 1) * 128;

  const unsigned short* At = Pp + ((long)(b * 528 + i * (i + 1) / 2) << 14);
  const unsigned short* Bp = VT + (long)b * DIM * SEQ + (long)n0 * SEQ;
  const float* lq = lbuf + (long)b * SEQ + m0;
  float* Op = O + ((long)b * SEQ + m0) * DIM;

  __shared__ unsigned short sA[128 * 64];   // P tile chunk  [128 q][64 kv]
  __shared__ unsigned short sB[256 * 64];   // V chunk       [256 d][64 kv]

  const int t = threadIdx.x, w = t >> 6, l = t & 63;
  const int wm = w >> 1, wn = w & 1;
  const int srow = l >> 3;
  const int scol = ((l & 7) ^ srow) * 8;
  const int frow = l & 15;

  f32x4 acc[4][8] = {};

  for (int k0 = 0; k0 < Keff; k0 += 64) {
    const unsigned short* Ak = At + ((long)(k0 >> 7) << 14) + (k0 & 64);
#pragma unroll
    for (int j = 0; j < 4; ++j) {
      const int c = 4 * w + j;
      gll16(Ak + (long)(c * 8 + srow) * 128 + scol, &sA[c * 512]);
    }
#pragma unroll
    for (int j = 0; j < 8; ++j) {
      const int c = 8 * w + j;
      gll16(Bp + (long)(c * 8 + srow) * SEQ + k0 + scol, &sB[c * 512]);
    }
    __syncthreads();
#pragma unroll
    for (int kk = 0; kk < 2; ++kk) {
      const int slot = (l >> 4) + 4 * kk;
      bf16x8 av[4], bv[8];
#pragma unroll
      for (int ii = 0; ii < 4; ++ii) {
        const int row = wm * 64 + ii * 16 + frow;
        av[ii] = *(const bf16x8*)(&sA[row * 64 + ((slot ^ (row & 7)) << 3)]);
      }
#pragma unroll
      for (int nj = 0; nj < 8; ++nj) {
        const int row = wn * 128 + nj * 16 + frow;
        bv[nj] = *(const bf16x8*)(&sB[row * 64 + ((slot ^ (row & 7)) << 3)]);
      }
#pragma unroll
      for (int mi = 0; mi < 4; ++mi)
#pragma unroll
        for (int nj = 0; nj < 8; ++nj)
          acc[mi][nj] = __builtin_amdgcn_mfma_f32_16x16x32_bf16(av[mi], bv[nj], acc[mi][nj], 0, 0, 0);
    }
    __syncthreads();
  }

  const int rb = wm * 64 + (l >> 4) * 4;        // tile-local q row
  const int cb = n0 + wn * 128 + frow;          // d col
#pragma unroll
  for (int mi = 0; mi < 4; ++mi)
#pragma unroll
    for (int r = 0; r < 4; ++r) {
      const int row = rb + mi * 16 + r;
      const float inv = 1.0f / lq[row];
#pragma unroll
      for (int nj = 0; nj < 8; ++nj)
        Op[(long)row * DIM + cb + nj * 16] = acc[mi][nj][r] * inv;
    }
}

extern "C" void kernel_launch(void* const* d_in, const int* in_sizes, int n_in,
                              void* d_out, int out_size, void* d_ws, size_t ws_size,
                              hipStream_t stream) {
  (void)in_sizes; (void)n_in; (void)out_size;
  const float* x  = (const float*)d_in[0];
  const float* wq = (const float*)d_in[1];
  const float* wk = (const float*)d_in[2];
  const float* wv = (const float*)d_in[3];
  float* out = (float*)d_out;

  const long NTOK = (long)SEQ * 4;
  unsigned short* xb  = (unsigned short*)d_ws;
  unsigned short* Qb  = xb + NTOK * DIM;
  unsigned short* Kb  = Qb + NTOK * DIM;
  unsigned short* VT  = Kb + NTOK * DIM;
  unsigned short* w3  = VT + NTOK * DIM;
  unsigned short* wqb = w3;
  unsigned short* wkb = wqb + DIM * DIM;
  unsigned short* wvb = wkb + DIM * DIM;
  unsigned short* Pp  = w3;

  const size_t base_b = 4ull * NTOK * DIM * 2ull;
  const size_t full_need = base_b + (2112ull << 14) * 2 + 4ull * NTOK;
  const bool full = ws_size >= full_need;
  const float scale = 0.03125f;

  cvt_bf16_kernel<<<2048, 256, 0, stream>>>(x, xb, (int)(NTOK * DIM / 4));
  cvt_w3_kernel<<<1024, 256, 0, stream>>>(wq, wk, wv, wqb);

  qk_proj_kernel<<<128 * 8, 256, 0, stream>>>(xb, wqb, wkb, Qb, Kb);
  vt_proj_kernel<<<8 * 128, 256, 0, stream>>>(wvb, xb, VT);

  if (full) {
    float* lbuf = (float*)(Pp + (2112ull << 14));
    sgemm_packed_kernel<<<4 * 528, 256, 0, stream>>>(Qb, Kb, Pp, scale);
    lsum_kernel<<<4096, 256, 0, stream>>>(Pp, lbuf);
    pv_kernel<<<4 * 4 * 32, 256, 0, stream>>>(Pp, VT, lbuf, out, 4);
  } else {
    float* lbuf = (float*)(Pp + (528ull << 14));
    for (int b = 0; b < 4; ++b) {
      sgemm_packed_kernel<<<528, 256, 0, stream>>>(
          Qb + (long)b * SEQ * DIM, Kb + (long)b * SEQ * DIM, Pp, scale);
      lsum_kernel<<<1024, 256, 0, stream>>>(Pp, lbuf);
      pv_kernel<<<4 * 32, 256, 0, stream>>>(
          Pp, VT + (long)b * DIM * SEQ, lbuf, out + (long)b * SEQ * DIM, 1);
    }
  }
}

// Round 9
// 340.770 us; speedup vs baseline: 1.0760x; 1.0447x over previous
//
#include <hip/hip_runtime.h>
#include <hip/hip_bf16.h>

// SingleHeadAttention: B=4, S=4096, D=1024, fp32 in/out, causal, interleaved RoPE.
// R9: pv load-balanced by DIAGONAL PAIRING — each block processes q-tiles (i, 31-i)
//     sequentially: (i+1)+(32-i) = 33 K-tiles = uniform work, no straggler tail
//     (R8 lesson: occupancy 9.8% from tail >> traffic win). R5 128x128 engine kept.

#define SEQ 4096
#define DIM 1024

typedef short bf16x8 __attribute__((ext_vector_type(8)));
typedef float f32x4 __attribute__((ext_vector_type(4)));

__device__ __forceinline__ unsigned short f2bf(float f) {
  unsigned int u = __float_as_uint(f);
  u += 0x7FFFu + ((u >> 16) & 1u);   // RNE
  return (unsigned short)(u >> 16);
}

// bijective XCD swizzle (grids % 8 == 0): XCD x gets work [x*nwg/8,(x+1)*nwg/8)
__device__ __forceinline__ int xcd_swz(int bid, int nwg) {
  return (bid & 7) * (nwg >> 3) + (bid >> 3);
}

__device__ __forceinline__ void gll16(const unsigned short* g, unsigned short* l) {
  __builtin_amdgcn_global_load_lds(
      (const __attribute__((address_space(1))) void*)g,
      (__attribute__((address_space(3))) void*)l, 16, 0, 0);
}

__global__ __launch_bounds__(256) void cvt_bf16_kernel(const float* __restrict__ in,
                                                       unsigned short* __restrict__ out,
                                                       int n4) {
  int stride = gridDim.x * blockDim.x;
  for (int j = blockIdx.x * blockDim.x + threadIdx.x; j < n4; j += stride) {
    float4 v = ((const float4*)in)[j];
    ushort4 o;
    o.x = f2bf(v.x); o.y = f2bf(v.y); o.z = f2bf(v.z); o.w = f2bf(v.w);
    ((ushort4*)out)[j] = o;
  }
}

__global__ __launch_bounds__(256) void cvt_w3_kernel(const float* __restrict__ a,
                                                     const float* __restrict__ b,
                                                     const float* __restrict__ c,
                                                     unsigned short* __restrict__ dst) {
  const int n4 = DIM * DIM / 4;
  int stride = gridDim.x * blockDim.x;
  for (int j = blockIdx.x * blockDim.x + threadIdx.x; j < 3 * n4; j += stride) {
    const float* src = j < n4 ? a : (j < 2 * n4 ? b : c);
    const int off = j < n4 ? j : (j < 2 * n4 ? j - n4 : j - 2 * n4);
    float4 v = ((const float4*)src)[off];
    ushort4 o;
    o.x = f2bf(v.x); o.y = f2bf(v.y); o.z = f2bf(v.z); o.w = f2bf(v.w);
    ((ushort4*)dst)[j] = o;
  }
}

// RoPE epilogue: pairs (2i,2i+1) are adjacent lanes (col parity == lane parity)
__device__ __forceinline__ void rope_store(const f32x4 (&acc)[4][4], unsigned short* C,
                                           int rbase, int cbase, int ldc) {
#pragma unroll
  for (int nj = 0; nj < 4; ++nj) {
    const int col = cbase + nj * 16;
    const float invfreq = exp2f(-0.025952563241307517f * (float)(col >> 1));
    const bool odd = (col & 1) != 0;
#pragma unroll
    for (int mi = 0; mi < 4; ++mi)
#pragma unroll
      for (int r = 0; r < 4; ++r) {
        const int row = rbase + mi * 16 + r;
        const float v = acc[mi][nj][r];
        const float p = __shfl_xor(v, 1, 64);
        const float ang = (float)(row & (SEQ - 1)) * invfreq;
        const float sn = __sinf(ang), cs = __cosf(ang);
        C[(long)row * ldc + col] = f2bf(odd ? (v * cs + p * sn) : (v * cs - p * sn));
      }
  }
}

// Fused Q+K projection (+RoPE). 128x128 tile, BK=64, swizzled LDS. [R2-verified]
__global__ __launch_bounds__(256, 2) void qk_proj_kernel(
    const unsigned short* __restrict__ X,
    const unsigned short* __restrict__ Wq,
    const unsigned short* __restrict__ Wk,
    unsigned short* __restrict__ Q,
    unsigned short* __restrict__ Ko) {
  const int bid = xcd_swz(blockIdx.x, gridDim.x);
  const int mt = bid >> 3, nt = bid & 7;
  const int m0 = mt * 128, n0 = nt * 128;

  __shared__ unsigned short sX[128 * 64];
  __shared__ unsigned short sQ[128 * 64];
  __shared__ unsigned short sK[128 * 64];

  const int t = threadIdx.x, w = t >> 6, l = t & 63;
  const int wm = w >> 1, wn = w & 1;
  const int srow = l >> 3;
  const int scol = ((l & 7) ^ srow) * 8;
  const int frow = l & 15;

  f32x4 cq[4][4] = {}, ck[4][4] = {};

  for (int k0 = 0; k0 < DIM; k0 += 64) {
#pragma unroll
    for (int j = 0; j < 4; ++j) {
      const int c = 4 * w + j;
      const int gr = c * 8 + srow;
      gll16(X  + (long)(m0 + gr) * DIM + k0 + scol, &sX[c * 512]);
      gll16(Wq + (long)(n0 + gr) * DIM + k0 + scol, &sQ[c * 512]);
      gll16(Wk + (long)(n0 + gr) * DIM + k0 + scol, &sK[c * 512]);
    }
    __syncthreads();
#pragma unroll
    for (int kk = 0; kk < 2; ++kk) {
      const int slot = (l >> 4) + 4 * kk;
      bf16x8 xa[4], bb[4];
#pragma unroll
      for (int i = 0; i < 4; ++i) {
        const int row = wm * 64 + i * 16 + frow;
        xa[i] = *(const bf16x8*)(&sX[row * 64 + ((slot ^ (row & 7)) << 3)]);
      }
#pragma unroll
      for (int i = 0; i < 4; ++i) {
        const int row = wn * 64 + i * 16 + frow;
        bb[i] = *(const bf16x8*)(&sQ[row * 64 + ((slot ^ (row & 7)) << 3)]);
      }
#pragma unroll
      for (int mi = 0; mi < 4; ++mi)
#pragma unroll
        for (int nj = 0; nj < 4; ++nj)
          cq[mi][nj] = __builtin_amdgcn_mfma_f32_16x16x32_bf16(xa[mi], bb[nj], cq[mi][nj], 0, 0, 0);
#pragma unroll
      for (int i = 0; i < 4; ++i) {
        const int row = wn * 64 + i * 16 + frow;
        bb[i] = *(const bf16x8*)(&sK[row * 64 + ((slot ^ (row & 7)) << 3)]);
      }
#pragma unroll
      for (int mi = 0; mi < 4; ++mi)
#pragma unroll
        for (int nj = 0; nj < 4; ++nj)
          ck[mi][nj] = __builtin_amdgcn_mfma_f32_16x16x32_bf16(xa[mi], bb[nj], ck[mi][nj], 0, 0, 0);
    }
    __syncthreads();
  }

  const int rbase = m0 + wm * 64 + (l >> 4) * 4;
  const int cbase = n0 + wn * 64 + frow;
  rope_store(cq, Q, rbase, cbase, DIM);
  rope_store(ck, Ko, rbase, cbase, DIM);
}

// V^T projection: VT[b][e][s] = sum_k Wv[e][k] * X[b*4096+s][k]. [R2-verified]
__global__ __launch_bounds__(256, 2) void vt_proj_kernel(
    const unsigned short* __restrict__ Wv,
    const unsigned short* __restrict__ X,
    unsigned short* __restrict__ VT) {
  const int bid = xcd_swz(blockIdx.x, gridDim.x);
  const int mt = bid >> 7, nt = bid & 127;
  const int m0 = mt * 128, n0 = nt * 128;

  __shared__ unsigned short sA[128 * 64];
  __shared__ unsigned short sB[128 * 64];

  const int t = threadIdx.x, w = t >> 6, l = t & 63;
  const int wm = w >> 1, wn = w & 1;
  const int srow = l >> 3;
  const int scol = ((l & 7) ^ srow) * 8;
  const int frow = l & 15;

  f32x4 acc[4][4] = {};

  for (int k0 = 0; k0 < DIM; k0 += 64) {
#pragma unroll
    for (int j = 0; j < 4; ++j) {
      const int c = 4 * w + j;
      const int gr = c * 8 + srow;
      gll16(Wv + (long)(m0 + gr) * DIM + k0 + scol, &sA[c * 512]);
      gll16(X  + (long)(n0 + gr) * DIM + k0 + scol, &sB[c * 512]);
    }
    __syncthreads();
#pragma unroll
    for (int kk = 0; kk < 2; ++kk) {
      const int slot = (l >> 4) + 4 * kk;
      bf16x8 av[4], bv[4];
#pragma unroll
      for (int i = 0; i < 4; ++i) {
        const int row = wm * 64 + i * 16 + frow;
        av[i] = *(const bf16x8*)(&sA[row * 64 + ((slot ^ (row & 7)) << 3)]);
      }
#pragma unroll
      for (int i = 0; i < 4; ++i) {
        const int row = wn * 64 + i * 16 + frow;
        bv[i] = *(const bf16x8*)(&sB[row * 64 + ((slot ^ (row & 7)) << 3)]);
      }
#pragma unroll
      for (int mi = 0; mi < 4; ++mi)
#pragma unroll
        for (int nj = 0; nj < 4; ++nj)
          acc[mi][nj] = __builtin_amdgcn_mfma_f32_16x16x32_bf16(av[mi], bv[nj], acc[mi][nj], 0, 0, 0);
    }
    __syncthreads();
  }

  const int rbase = m0 + wm * 64 + (l >> 4) * 4;
  const int cbase = n0 + wn * 64 + frow;
#pragma unroll
  for (int mi = 0; mi < 4; ++mi)
#pragma unroll
    for (int nj = 0; nj < 4; ++nj)
#pragma unroll
      for (int r = 0; r < 4; ++r) {
        const int row = rbase + mi * 16 + r;
        const int col = cbase + nj * 16;
        VT[(long)(col >> 12) * (DIM * SEQ) + (long)row * SEQ + (col & (SEQ - 1))] =
            f2bf(acc[mi][nj][r]);
      }
}

// Scores -> P = exp(s*scale) bf16, packed triangular 128-tiles. [R5-verified]
__global__ __launch_bounds__(256, 2) void sgemm_packed_kernel(
    const unsigned short* __restrict__ Q,
    const unsigned short* __restrict__ K,
    unsigned short* __restrict__ Pp,
    float scale) {
  const int t0 = xcd_swz(blockIdx.x, gridDim.x);
  const int b = t0 / 528;
  const int t2 = t0 - b * 528;
  int i = (int)((sqrtf(8.f * (float)t2 + 1.f) - 1.f) * 0.5f);
  while ((i + 1) * (i + 2) / 2 <= t2) ++i;
  while (i * (i + 1) / 2 > t2) --i;
  const int j = t2 - i * (i + 1) / 2;

  const unsigned short* A = Q + ((long)b * SEQ + i * 128) * DIM;
  const unsigned short* B = K + ((long)b * SEQ + j * 128) * DIM;

  __shared__ unsigned short sA[128 * 64];
  __shared__ unsigned short sB[128 * 64];

  const int t = threadIdx.x, w = t >> 6, l = t & 63;
  const int wm = w >> 1, wn = w & 1;
  const int srow = l >> 3;
  const int scol = ((l & 7) ^ srow) * 8;
  const int frow = l & 15;

  f32x4 acc[4][4] = {};

  for (int k0 = 0; k0 < DIM; k0 += 64) {
#pragma unroll
    for (int jj = 0; jj < 4; ++jj) {
      const int c = 4 * w + jj;
      const int gr = c * 8 + srow;
      gll16(A + (long)gr * DIM + k0 + scol, &sA[c * 512]);
      gll16(B + (long)gr * DIM + k0 + scol, &sB[c * 512]);
    }
    __syncthreads();
#pragma unroll
    for (int kk = 0; kk < 2; ++kk) {
      const int slot = (l >> 4) + 4 * kk;
      bf16x8 av[4], bv[4];
#pragma unroll
      for (int ii = 0; ii < 4; ++ii) {
        const int row = wm * 64 + ii * 16 + frow;
        av[ii] = *(const bf16x8*)(&sA[row * 64 + ((slot ^ (row & 7)) << 3)]);
      }
#pragma unroll
      for (int ii = 0; ii < 4; ++ii) {
        const int row = wn * 64 + ii * 16 + frow;
        bv[ii] = *(const bf16x8*)(&sB[row * 64 + ((slot ^ (row & 7)) << 3)]);
      }
#pragma unroll
      for (int mi = 0; mi < 4; ++mi)
#pragma unroll
        for (int nj = 0; nj < 4; ++nj)
          acc[mi][nj] = __builtin_amdgcn_mfma_f32_16x16x32_bf16(av[mi], bv[nj], acc[mi][nj], 0, 0, 0);
    }
    __syncthreads();
  }

  unsigned short* Ct = Pp + ((long)(b * 528 + t2) << 14);
  const int rb = wm * 64 + (l >> 4) * 4;
  const int cb = wn * 64 + frow;
  const bool diagt = (j == i);
#pragma unroll
  for (int mi = 0; mi < 4; ++mi)
#pragma unroll
    for (int nj = 0; nj < 4; ++nj)
#pragma unroll
      for (int r = 0; r < 4; ++r) {
        const int row = rb + mi * 16 + r;
        const int col = cb + nj * 16;
        float p = __expf(acc[mi][nj][r] * scale);
        if (diagt && col > row) p = 0.f;
        Ct[row * 128 + col] = f2bf(p);
      }
}

// Row sums of P: l[q] = sum_kv P[q][kv]. One wave per row; coalesced 4B/lane.
__global__ __launch_bounds__(256) void lsum_kernel(const unsigned short* __restrict__ Pp,
                                                   float* __restrict__ lbuf) {
  const int wid = blockIdx.x * 4 + (threadIdx.x >> 6);
  const int l = threadIdx.x & 63;
  const int b = wid >> 12;
  const int qrow = wid & (SEQ - 1);
  const int i = qrow >> 7, r = qrow & 127;
  const unsigned short* base =
      Pp + ((long)(b * 528 + i * (i + 1) / 2) << 14) + r * 128 + l * 2;

  float sum = 0.f;
  for (int j = 0; j <= i; ++j) {
    const unsigned int v = *(const unsigned int*)(base + ((long)j << 14));
    sum += __uint_as_float(v << 16) + __uint_as_float(v & 0xffff0000u);
  }
#pragma unroll
  for (int o = 32; o; o >>= 1) sum += __shfl_xor(sum, o, 64);
  if (l == 0) lbuf[wid] = sum;
}

// PV: O[q][d] = (1/l[q]) * sum_kv P[q][kv] * V^T[d][kv].
// DIAGONAL-PAIRED: block processes q-tiles i and 31-i sequentially ->
// (i+1)+(32-i) = 33 K-tiles per block, uniform work, no straggler tail.
// 128q x 128d per phase, d-innermost XCD-chunked work order.
__global__ __launch_bounds__(256, 2) void pv_kernel(
    const unsigned short* __restrict__ Pp,
    const unsigned short* __restrict__ VT,
    const float* __restrict__ lbuf,
    float* __restrict__ O,
    int nb) {
  const int work = xcd_swz(blockIdx.x, gridDim.x);
  const int d = work & 7;
  const int rest = work >> 3;
  const int b = rest % nb;
  const int pr = rest / nb;                  // 0..15
  const int n0 = d * 128;

  const unsigned short* Bp = VT + (long)b * DIM * SEQ + (long)n0 * SEQ;

  __shared__ unsigned short sA[128 * 64];
  __shared__ unsigned short sB[128 * 64];

  const int t = threadIdx.x, w = t >> 6, l = t & 63;
  const int wm = w >> 1, wn = w & 1;
  const int srow = l >> 3;
  const int scol = ((l & 7) ^ srow) * 8;
  const int frow = l & 15;

#pragma unroll
  for (int ph = 0; ph < 2; ++ph) {
    const int i = ph ? (31 - pr) : pr;
    const int m0 = i * 128;
    const int Keff = (i + 1) * 128;
    const unsigned short* At = Pp + ((long)(b * 528 + i * (i + 1) / 2) << 14);
    const float* lq = lbuf + (long)b * SEQ + m0;
    float* Op = O + ((long)b * SEQ + m0) * DIM;

    f32x4 acc[4][4] = {};

    for (int k0 = 0; k0 < Keff; k0 += 64) {
      const unsigned short* Ak = At + ((long)(k0 >> 7) << 14) + (k0 & 64);
#pragma unroll
      for (int j = 0; j < 4; ++j) {
        const int c = 4 * w + j;
        const int gr = c * 8 + srow;
        gll16(Ak + (long)gr * 128 + scol, &sA[c * 512]);
        gll16(Bp + (long)gr * SEQ + k0 + scol, &sB[c * 512]);
      }
      __syncthreads();
#pragma unroll
      for (int kk = 0; kk < 2; ++kk) {
        const int slot = (l >> 4) + 4 * kk;
        bf16x8 av[4], bv[4];
#pragma unroll
        for (int ii = 0; ii < 4; ++ii) {
          const int row = wm * 64 + ii * 16 + frow;
          av[ii] = *(const bf16x8*)(&sA[row * 64 + ((slot ^ (row & 7)) << 3)]);
        }
#pragma unroll
        for (int ii = 0; ii < 4; ++ii) {
          const int row = wn * 64 + ii * 16 + frow;
          bv[ii] = *(const bf16x8*)(&sB[row * 64 + ((slot ^ (row & 7)) << 3)]);
        }
#pragma unroll
        for (int mi = 0; mi < 4; ++mi)
#pragma unroll
          for (int nj = 0; nj < 4; ++nj)
            acc[mi][nj] = __builtin_amdgcn_mfma_f32_16x16x32_bf16(av[mi], bv[nj], acc[mi][nj], 0, 0, 0);
      }
      __syncthreads();
    }

    const int rb = wm * 64 + (l >> 4) * 4;
    const int cb = n0 + wn * 64 + frow;
#pragma unroll
    for (int mi = 0; mi < 4; ++mi)
#pragma unroll
      for (int r = 0; r < 4; ++r) {
        const int row = rb + mi * 16 + r;
        const float inv = 1.0f / lq[row];
#pragma unroll
        for (int nj = 0; nj < 4; ++nj)
          Op[(long)row * DIM + cb + nj * 16] = acc[mi][nj][r] * inv;
      }
  }
}

extern "C" void kernel_launch(void* const* d_in, const int* in_sizes, int n_in,
                              void* d_out, int out_size, void* d_ws, size_t ws_size,
                              hipStream_t stream) {
  (void)in_sizes; (void)n_in; (void)out_size;
  const float* x  = (const float*)d_in[0];
  const float* wq = (const float*)d_in[1];
  const float* wk = (const float*)d_in[2];
  const float* wv = (const float*)d_in[3];
  float* out = (float*)d_out;

  const long NTOK = (long)SEQ * 4;
  unsigned short* xb  = (unsigned short*)d_ws;
  unsigned short* Qb  = xb + NTOK * DIM;
  unsigned short* Kb  = Qb + NTOK * DIM;
  unsigned short* VT  = Kb + NTOK * DIM;
  unsigned short* w3  = VT + NTOK * DIM;
  unsigned short* wqb = w3;
  unsigned short* wkb = wqb + DIM * DIM;
  unsigned short* wvb = wkb + DIM * DIM;
  unsigned short* Pp  = w3;

  const size_t base_b = 4ull * NTOK * DIM * 2ull;
  const size_t full_need = base_b + (2112ull << 14) * 2 + 4ull * NTOK;
  const bool full = ws_size >= full_need;
  const float scale = 0.03125f;

  cvt_bf16_kernel<<<2048, 256, 0, stream>>>(x, xb, (int)(NTOK * DIM / 4));
  cvt_w3_kernel<<<1024, 256, 0, stream>>>(wq, wk, wv, wqb);

  qk_proj_kernel<<<128 * 8, 256, 0, stream>>>(xb, wqb, wkb, Qb, Kb);
  vt_proj_kernel<<<8 * 128, 256, 0, stream>>>(wvb, xb, VT);

  if (full) {
    float* lbuf = (float*)(Pp + (2112ull << 14));
    sgemm_packed_kernel<<<4 * 528, 256, 0, stream>>>(Qb, Kb, Pp, scale);
    lsum_kernel<<<4096, 256, 0, stream>>>(Pp, lbuf);
    pv_kernel<<<16 * 4 * 8, 256, 0, stream>>>(Pp, VT, lbuf, out, 4);
  } else {
    float* lbuf = (float*)(Pp + (528ull << 14));
    for (int b = 0; b < 4; ++b) {
      sgemm_packed_kernel<<<528, 256, 0, stream>>>(
          Qb + (long)b * SEQ * DIM, Kb + (long)b * SEQ * DIM, Pp, scale);
      lsum_kernel<<<1024, 256, 0, stream>>>(Pp, lbuf);
      pv_kernel<<<16 * 8, 256, 0, stream>>>(
          Pp, VT + (long)b * DIM * SEQ, lbuf, out + (long)b * SEQ * DIM, 1);
    }
  }
}